// Round 1
// baseline (174.937 us; speedup 1.0000x reference)
//
#include <hip/hip_runtime.h>

#define B_ 8
#define H_ 512
#define W_ 1024

// ---------------- Stage 1: boundaries + dist + 4 masked-average iterations ----
#define TILE 32
#define HP 8                     // pred halo
#define HB 7                     // boundary halo
#define HD 4                     // dist / evolving-image halo
#define RP (TILE + 2*HP)         // 48
#define RB (TILE + 2*HB)         // 46
#define RD (TILE + 2*HD)         // 40

__device__ __forceinline__ int clampi(int v, int lo, int hi) {
    return v < lo ? lo : (v > hi ? hi : v);
}
__device__ __forceinline__ int imax(int a, int b) { return a > b ? a : b; }
__device__ __forceinline__ int imin(int a, int b) { return a < b ? a : b; }

__global__ __launch_bounds__(256)
void bsws_stage1(const float* __restrict__ xg, const int* __restrict__ predg,
                 float* __restrict__ outg)
{
    __shared__ int           sPred[RP * RP];
    __shared__ unsigned char sBnd[RB * RB];
    __shared__ unsigned char sDist[RD * RD];
    __shared__ float         sA[RD * RD];
    __shared__ float         sBuf[RD * RD];

    const int tid = threadIdx.x;
    const int x0 = blockIdx.x * TILE;
    const int y0 = blockIdx.y * TILE;
    const size_t plane = (size_t)H_ * W_;
    const int*   pp = predg + blockIdx.z * plane;
    const float* xp = xg    + blockIdx.z * plane;
    float*       op = outg  + blockIdx.z * plane;

    // ---- load prediction region (sentinel -1 for out-of-image) ----
    for (int i = tid; i < RP * RP; i += 256) {
        int ry = i / RP, rx = i - ry * RP;
        int gy = y0 - HP + ry, gx = x0 - HP + rx;
        int v = -1;
        if (gy >= 0 && gy < H_ && gx >= 0 && gx < W_) v = pp[(size_t)gy * W_ + gx];
        sPred[i] = v;
    }
    __syncthreads();

    // ---- boundary map: max over cross (NEG pad => ignore OOB) != min over 3x3 (POS pad => ignore OOB)
    for (int i = tid; i < RB * RB; i += 256) {
        int ry = i / RB, rx = i - ry * RB;
        int py = ry + (HP - HB), px = rx + (HP - HB);
        int c = sPred[py * RP + px];
        unsigned char bb = 0;
        if (c >= 0) {   // in-image center
            int up = sPred[(py - 1) * RP + px];
            int dn = sPred[(py + 1) * RP + px];
            int lf = sPred[py * RP + px - 1];
            int rt = sPred[py * RP + px + 1];
            // sentinel -1 < any label, so plain max ignores OOB
            int mx = imax(imax(c, up), imax(dn, imax(lf, rt)));
            int mn = c;
            #pragma unroll
            for (int dy = -1; dy <= 1; ++dy)
                #pragma unroll
                for (int dx = -1; dx <= 1; ++dx) {
                    int v = sPred[(py + dy) * RP + (px + dx)];
                    if (v >= 0 && v < mn) mn = v;  // ignore OOB for the min
                }
            bb = (mx != mn) ? 1 : 0;
        }
        sBnd[i] = bb;
    }
    __syncthreads();

    // ---- L1 distance to nearest boundary, capped at 4 ----
    for (int i = tid; i < RD * RD; i += 256) {
        int ry = i / RD, rx = i - ry * RD;
        int by = ry + (HB - HD), bx = rx + (HB - HD);
        int d = 4;
        #pragma unroll
        for (int dy = -3; dy <= 3; ++dy) {
            int ady = dy < 0 ? -dy : dy;
            for (int dx = -(3 - ady); dx <= 3 - ady; ++dx) {
                if (sBnd[(by + dy) * RB + (bx + dx)]) {
                    int adx = dx < 0 ? -dx : dx;
                    int l1 = ady + adx;
                    if (l1 < d) d = l1;
                }
            }
        }
        sDist[i] = (unsigned char)d;
    }

    // ---- load x region with edge clamp ----
    for (int i = tid; i < RD * RD; i += 256) {
        int ry = i / RD, rx = i - ry * RD;
        int gy = clampi(y0 - HD + ry, 0, H_ - 1);
        int gx = clampi(x0 - HD + rx, 0, W_ - 1);
        sA[i] = xp[(size_t)gy * W_ + gx];
    }
    __syncthreads();

    float* cur = sA;
    float* nxt = sBuf;
    const int oy = y0 - HD, ox = x0 - HD;

    #pragma unroll
    for (int it = 0; it < 4; ++it) {
        const int r = 3 - it;                 // mask = (dist > r)
        const int lo = HD - r;                // compute region: tile + halo r
        const int n1 = TILE + 2 * r;
        for (int i = tid; i < n1 * n1; i += 256) {
            int q  = i / n1;
            int ry = lo + q, rx = lo + (i - q * n1);
            int gy = oy + ry, gx = ox + rx;
            if (gy >= 0 && gy < H_ && gx >= 0 && gx < W_) {
                float center = cur[ry * RD + rx];
                float res = center;
                if ((int)sDist[ry * RD + rx] <= r) {  // mask==0 at p: replace by masked avg
                    float ysum = 0.f;
                    int n = 0;
                    #pragma unroll
                    for (int dy = -1; dy <= 1; ++dy) {
                        int qy = clampi(gy + dy, 0, H_ - 1) - oy;
                        #pragma unroll
                        for (int dx = -1; dx <= 1; ++dx) {
                            int qx = clampi(gx + dx, 0, W_ - 1) - ox;
                            int mq = ((int)sDist[qy * RD + qx] > r) ? 1 : 0;
                            n += mq;
                            if (mq) ysum += cur[qy * RD + qx];
                        }
                    }
                    if (n > 0) res = ysum / (float)n;
                }
                nxt[ry * RD + rx] = res;
            }
        }
        __syncthreads();
        float* t = cur; cur = nxt; nxt = t;
    }

    // ---- store tile ----
    for (int i = tid; i < TILE * TILE; i += 256) {
        int ty = i / TILE, tx = i - ty * TILE;
        int gy = y0 + ty, gx = x0 + tx;
        if (gy < H_ && gx < W_)
            op[(size_t)gy * W_ + gx] = cur[(ty + HD) * RD + (tx + HD)];
    }
}

// ---------------- Stage 2: separable dilated Gaussian (7 taps, dilation 6, edge pad 18)
#define GT 32
#define GH 18
#define GR (GT + 2*GH)   // 68

__global__ __launch_bounds__(256)
void bsws_stage2(const float* __restrict__ ing, float* __restrict__ outg)
{
    __shared__ float sIn[GR][GR + 1];  // 68 x 69 (pad to dodge conflicts)
    __shared__ float sH[GR][GT];       // 68 x 32

    const int tid = threadIdx.x;
    const int x0 = blockIdx.x * GT;
    const int y0 = blockIdx.y * GT;
    const size_t plane = (size_t)H_ * W_;
    const float* ip = ing  + blockIdx.z * plane;
    float*       op = outg + blockIdx.z * plane;

    // normalized separable 1D Gaussian weights, sigma=1, taps at 0..6 (center 3)
    const float W0c = 0.39905027965f;  // center
    const float W1c = 0.24203622800f;  // +-1 tap (offset 6)
    const float W2c = 0.05400558260f;  // +-2 tap (offset 12)
    const float W3c = 0.00443304810f;  // +-3 tap (offset 18)

    for (int i = tid; i < GR * GR; i += 256) {
        int ry = i / GR, rx = i - ry * GR;
        int gy = clampi(y0 - GH + ry, 0, H_ - 1);
        int gx = clampi(x0 - GH + rx, 0, W_ - 1);
        sIn[ry][rx] = ip[(size_t)gy * W_ + gx];
    }
    __syncthreads();

    // horizontal pass: rows [0,GR), cols of the tile only
    for (int i = tid; i < GR * GT; i += 256) {
        int ry = i / GT, cx = i - (i / GT) * GT;
        const float* row = &sIn[ry][0];
        float acc = W3c * (row[cx]      + row[cx + 36])
                  + W2c * (row[cx + 6]  + row[cx + 30])
                  + W1c * (row[cx + 12] + row[cx + 24])
                  + W0c *  row[cx + 18];
        sH[ry][cx] = acc;
    }
    __syncthreads();

    // vertical pass + store
    for (int i = tid; i < GT * GT; i += 256) {
        int ty = i / GT, tx = i - (i / GT) * GT;
        float acc = W3c * (sH[ty][tx]      + sH[ty + 36][tx])
                  + W2c * (sH[ty + 6][tx]  + sH[ty + 30][tx])
                  + W1c * (sH[ty + 12][tx] + sH[ty + 24][tx])
                  + W0c *  sH[ty + 18][tx];
        int gy = y0 + ty, gx = x0 + tx;
        if (gy < H_ && gx < W_)
            op[(size_t)gy * W_ + gx] = acc;
    }
}

extern "C" void kernel_launch(void* const* d_in, const int* in_sizes, int n_in,
                              void* d_out, int out_size, void* d_ws, size_t ws_size,
                              hipStream_t stream) {
    const float* x    = (const float*)d_in[0];
    const int*   pred = (const int*)d_in[1];
    float*       out  = (float*)d_out;
    float*       mid  = (float*)d_ws;   // needs B_*H_*W_*4 = 16.78 MB

    dim3 grid(W_ / TILE, H_ / TILE, B_);
    bsws_stage1<<<grid, dim3(256), 0, stream>>>(x, pred, mid);
    bsws_stage2<<<grid, dim3(256), 0, stream>>>(mid, out);
}